// Round 3
// baseline (609.689 us; speedup 1.0000x reference)
//
#include <hip/hip_runtime.h>

// out = ((1 + cos)/2 + 1e-8)/0.05 = 10*cos + 10 + 2e-7
// cos = normalize(emb) @ normalize(weight)^T
// emb: 65536x768 f32, weight: 1024x768 f32, out: 65536x1024 f32
//
// Fused design: GEMM reads emb (A) directly as f32, casts to bf16 in-register
// during staging, and accumulates per-row sum-of-squares on the fly; the
// epilogue scales by rsqrt(ssq). weight (B) is pre-normalized to bf16 by a
// tiny prep kernel. Software pipeline: global->reg prefetch of iter k+1
// issued before iter k's MFMA phase (latency hidden), single-buffer LDS.

#define N_EMB 65536
#define N_W   1024
#define DIM   768

typedef __attribute__((ext_vector_type(4))) float f32x4;
typedef __attribute__((ext_vector_type(8))) __bf16 bf16x8;

__device__ __forceinline__ unsigned short f2bf(float x) {
    unsigned int u = __float_as_uint(x);
    u += 0x7FFF + ((u >> 16) & 1);      // round-to-nearest-even
    return (unsigned short)(u >> 16);
}

// Normalize weight rows (f32) and cast to bf16. One wave per row.
__global__ __launch_bounds__(256) void prep_b_kernel(
    const float* __restrict__ weight, unsigned short* __restrict__ B)
{
    const int wave = threadIdx.x >> 6, lane = threadIdx.x & 63;
    const int row = blockIdx.x * 4 + wave;
    const float4* s4 = (const float4*)(weight + (size_t)row * DIM);
    float4 v[3];
    float ss = 0.f;
#pragma unroll
    for (int i = 0; i < 3; i++) {
        v[i] = s4[lane + 64 * i];
        ss += v[i].x * v[i].x + v[i].y * v[i].y + v[i].z * v[i].z + v[i].w * v[i].w;
    }
#pragma unroll
    for (int off = 32; off > 0; off >>= 1) ss += __shfl_xor(ss, off);
    float sc = 1.0f / fmaxf(sqrtf(ss), 1e-8f);
    ushort4* d4 = (ushort4*)(B + (size_t)row * DIM);
#pragma unroll
    for (int i = 0; i < 3; i++) {
        ushort4 o;
        o.x = f2bf(v[i].x * sc); o.y = f2bf(v[i].y * sc);
        o.z = f2bf(v[i].z * sc); o.w = f2bf(v[i].w * sc);
        d4[lane + 64 * i] = o;
    }
}

__device__ __forceinline__ void cvt_ssq(const f32x4 lv[4], bf16x8 o[2], float& ssq) {
#pragma unroll
    for (int h = 0; h < 2; h++) {
#pragma unroll
        for (int e = 0; e < 8; e++) {
            float x = lv[h * 2 + (e >> 2)][e & 3];
            o[h][e] = (__bf16)x;                 // RNE cvt_pk_bf16_f32
            ssq = fmaf(x, x, ssq);
        }
    }
}

// C[M,N] tile 128x128, BK=32, 256 threads = 4 waves (2x2), each wave 64x64 via
// 4x4 of mfma_f32_16x16x32_bf16. LDS [ko=4][row=128] x bf16x8, conflict-free.
// XCD swizzle: b -> xcd=b&7, s=b>>3, row_tile=xcd*64+s/8, col_tile=s%8 so each
// XCD keeps its A row-tiles + all of B resident in its 4MB L2.
__global__ __launch_bounds__(256) void cos_gemm_fused(
    const float* __restrict__ A, const unsigned short* __restrict__ Bn,
    float* __restrict__ out)
{
    __shared__ bf16x8 As[512];   // 8 KB
    __shared__ bf16x8 Bs[512];   // 8 KB
    const int t = threadIdx.x;
    const int lane = t & 63, wave = t >> 6;
    const int wm = wave & 1, wn = wave >> 1;
    const int quad = lane >> 4, l16 = lane & 15;

    const int b = blockIdx.x;
    const int xcd = b & 7, s = b >> 3;
    const int row0 = (xcd * 64 + (s >> 3)) * 128;
    const int col0 = (s & 7) * 128;

    // staging assignment: thread t covers row/col (t>>1), k-halfchunk (t&1)*16
    const int rowA = t >> 1, ch = t & 1;
    const f32x4*  Ag = (const f32x4*)(A + (size_t)(row0 + rowA) * DIM + ch * 16);
    const bf16x8* Bg = (const bf16x8*)(Bn + (size_t)(col0 + rowA) * DIM + ch * 16);

    f32x4 acc[4][4] = {};
    float ssq = 0.f;

    bf16x8 abf[2], bbf[2];   // staged data for the upcoming iteration
    {
        f32x4 lv[4];
#pragma unroll
        for (int i = 0; i < 4; i++) lv[i] = Ag[i];
        bbf[0] = Bg[0]; bbf[1] = Bg[1];
        cvt_ssq(lv, abf, ssq);
    }

    for (int k0 = 0; k0 < DIM; k0 += 32) {
        __syncthreads();                       // prior iter's frag reads done
        As[(ch * 2 + 0) * 128 + rowA] = abf[0];
        As[(ch * 2 + 1) * 128 + rowA] = abf[1];
        Bs[(ch * 2 + 0) * 128 + rowA] = bbf[0];
        Bs[(ch * 2 + 1) * 128 + rowA] = bbf[1];
        __syncthreads();                       // writes visible

        // issue prefetch for k0+32 (latency covered by the MFMA phase below)
        const int kn = k0 + 32;
        f32x4 lv[4];
        bf16x8 bnx0, bnx1;
        if (kn < DIM) {
#pragma unroll
            for (int i = 0; i < 4; i++) lv[i] = Ag[kn / 4 + i];
            bnx0 = Bg[kn / 8]; bnx1 = Bg[kn / 8 + 1];
        }

        bf16x8 af[4], bfr[4];
#pragma unroll
        for (int i = 0; i < 4; i++) af[i]  = As[quad * 128 + wm * 64 + i * 16 + l16];
#pragma unroll
        for (int j = 0; j < 4; j++) bfr[j] = Bs[quad * 128 + wn * 64 + j * 16 + l16];
#pragma unroll
        for (int i = 0; i < 4; i++)
#pragma unroll
            for (int j = 0; j < 4; j++)
                acc[i][j] = __builtin_amdgcn_mfma_f32_16x16x32_bf16(af[i], bfr[j], acc[i][j], 0, 0, 0);

        if (kn < DIM) {
            cvt_ssq(lv, abf, ssq);             // vmcnt wait lands here, after MFMAs
            bbf[0] = bnx0; bbf[1] = bnx1;
        }
    }

    // A-row norms: thread t holds ssq for row t>>1, half t&1
    __syncthreads();                           // final frag reads done, LDS reusable
    float* sc = (float*)As;
    sc[t] = ssq;
    __syncthreads();
    float* invA = (float*)Bs;
    if (t < 128) invA[t] = rsqrtf(fmaxf(sc[2 * t] + sc[2 * t + 1], 1e-16f));
    __syncthreads();

    // C/D layout: col = lane&15, row = quad*4 + reg. Non-temporal: C is
    // write-once; keep L2 for A/B residency.
#pragma unroll
    for (int i = 0; i < 4; i++) {
#pragma unroll
        for (int r = 0; r < 4; r++) {
            const int rl = wm * 64 + i * 16 + quad * 4 + r;
            const float scale = invA[rl] * 10.0f;
            float* orow = out + (size_t)(row0 + rl) * N_W + col0 + wn * 64 + l16;
#pragma unroll
            for (int j = 0; j < 4; j++)
                __builtin_nontemporal_store(fmaf(acc[i][j][r], scale, 10.0f), orow + j * 16);
        }
    }
}

extern "C" void kernel_launch(void* const* d_in, const int* in_sizes, int n_in,
                              void* d_out, int out_size, void* d_ws, size_t ws_size,
                              hipStream_t stream) {
    const float* emb    = (const float*)d_in[0];
    const float* weight = (const float*)d_in[1];
    unsigned short* B = (unsigned short*)d_ws;     // 1024*768 bf16 (1.5 MB)
    float* out = (float*)d_out;

    prep_b_kernel<<<N_W / 4, 256, 0, stream>>>(weight, B);
    cos_gemm_fused<<<4096, 256, 0, stream>>>(emb, B, out);
}